// Round 3
// baseline (4728.053 us; speedup 1.0000x reference)
//
#include <hip/hip_runtime.h>
#include <math.h>

#define BB 8
#define LL 196
#define DD 384
#define NDEPTH 24
#define NST 16
#define RRANK 24
#define HHID 1024
#define MROWS (BB*LL)   /* 1568 */
#define NCH 14
#define CHL 14

typedef float f32x4 __attribute__((ext_vector_type(4)));
typedef short s16x8 __attribute__((ext_vector_type(8)));
typedef short s16x4 __attribute__((ext_vector_type(4)));
typedef __bf16 b16x8 __attribute__((ext_vector_type(8)));
typedef unsigned short u16;
typedef unsigned int u32;

__device__ __forceinline__ float sigmoidf_(float x){ return 1.f/(1.f+__expf(-x)); }

__device__ __forceinline__ u16 f2bf(float f){
    u32 u = __builtin_bit_cast(u32, f);
    u32 r = (u + 0x7fffu + ((u >> 16) & 1u)) >> 16;   // RNE
    return (u16)r;
}

// ---- MFMA wrapper: SFINAE hedge over builtin operand type ----
template<typename V>
__device__ __forceinline__ auto mfma_try(V a, V b, f32x4 c, int)
    -> decltype(__builtin_amdgcn_mfma_f32_16x16x32_bf16(a, b, c, 0, 0, 0))
{ return __builtin_amdgcn_mfma_f32_16x16x32_bf16(a, b, c, 0, 0, 0); }

template<typename V>
__device__ __forceinline__ f32x4 mfma_try(V a, V b, f32x4 c, long)
{
    return __builtin_amdgcn_mfma_f32_16x16x32_bf16(
        __builtin_bit_cast(b16x8, a), __builtin_bit_cast(b16x8, b), c, 0, 0, 0);
}
__device__ __forceinline__ f32x4 mfma_bf16(s16x8 a, s16x8 b, f32x4 c){ return mfma_try(a, b, c, 0); }

// ---------------- LayerNorm: BF=1 -> bf16 out, BF=0 -> f32 out ----------------
template<int BF>
__global__ __launch_bounds__(64) void ln_k(const float* __restrict__ X,
    const float* __restrict__ w, const float* __restrict__ b, void* __restrict__ Yv)
{
    int row = blockIdx.x;
    int lane = threadIdx.x;
    const float* x = X + (size_t)row*DD;
    float v[6]; float s=0.f, s2=0.f;
    #pragma unroll
    for (int j=0;j<6;j++){ float t = x[lane + j*64]; v[j]=t; s+=t; s2+=t*t; }
    #pragma unroll
    for (int o=32;o>=1;o>>=1){ s += __shfl_xor(s,o); s2 += __shfl_xor(s2,o); }
    float m = s*(1.f/DD);
    float var = s2*(1.f/DD) - m*m;
    float rstd = rsqrtf(var + 1e-5f);
    #pragma unroll
    for (int j=0;j<6;j++){
        int c = lane + j*64;
        float val = (v[j]-m)*rstd*w[c] + b[c];
        if (BF) ((u16*)Yv)[(size_t)row*DD + c] = f2bf(val);
        else    ((float*)Yv)[(size_t)row*DD + c] = val;
    }
}

// ---------------- Patch gather -> bf16 (B*L, 768) ----------------
__global__ void gather_k(const float* __restrict__ x, u16* __restrict__ P)
{
    int idx = blockIdx.x*blockDim.x + threadIdx.x;
    if (idx >= MROWS*768) return;
    int k = idx % 768;
    int bl = idx / 768;
    int l = bl % LL;
    int b = bl / LL;
    int c = k >> 8;
    int rem = k & 255;
    int dy = rem >> 4, dx = rem & 15;
    int py = l / 14, px = l % 14;
    P[idx] = f2bf(x[(((size_t)b*3 + c)*224 + (py*16+dy))*224 + (px*16+dx)]);
}

// ---------------- fused conv+SiLU+x_proj: writes xa (side) and dbc = xa @ xp_w^T ----------------
__global__ __launch_bounds__(256) void xprojconv_k(
    const float* __restrict__ xz, const float* __restrict__ cw, const float* __restrict__ cb,
    const float* __restrict__ W, float* __restrict__ xa, float* __restrict__ dbc)
{
    __shared__ float As[16][68];
    __shared__ float Ws1[16][68];
    const int N = 56, K = DD;
    int tid = threadIdx.x;
    int tx = tid & 15, ty = tid >> 4;
    int row0 = blockIdx.y*64;

    int ldr  = tid >> 2;          // 0..63
    int ldk4 = (tid & 3) << 2;

    float acc[4][4] = {{0.f}};

    int gr = row0 + ldr;
    bool aok = gr < MROWS;
    int bl = aok ? gr : 0;
    int l = bl % LL;
    const float* xrow = xz + (size_t)bl*768;
    const float* Wrow = W + (size_t)ldr*K;
    bool wok = ldr < N;

    for (int kt=0; kt<24; kt++){
        int kg = kt*16 + ldk4;
        float4 av = {0,0,0,0};
        if (aok){
            float o[4];
            #pragma unroll
            for (int jj=0;jj<4;jj++){
                int d = kg + jj;
                float a = cb[d];
                #pragma unroll
                for (int k=0;k<4;k++){
                    int ls = l + k - 3;
                    if (ls >= 0) a = fmaf(xrow[(k-3)*768 + d], cw[d*4+k], a);
                }
                o[jj] = a * sigmoidf_(a);
            }
            av.x=o[0]; av.y=o[1]; av.z=o[2]; av.w=o[3];
            *(float4*)(xa + (size_t)gr*DD + kg) = av;
        }
        float4 wv = {0,0,0,0};
        if (wok) wv = *(const float4*)(Wrow + kg);
        __syncthreads();
        As [ldk4+0][ldr]=av.x; As [ldk4+1][ldr]=av.y; As [ldk4+2][ldr]=av.z; As [ldk4+3][ldr]=av.w;
        Ws1[ldk4+0][ldr]=wv.x; Ws1[ldk4+1][ldr]=wv.y; Ws1[ldk4+2][ldr]=wv.z; Ws1[ldk4+3][ldr]=wv.w;
        __syncthreads();
        #pragma unroll
        for (int k=0;k<16;k++){
            const float4 a  = *(const float4*)&As[k][ty<<2];
            const float4 b1 = *(const float4*)&Ws1[k][tx<<2];
            float ar[4] = {a.x,a.y,a.z,a.w};
            float br[4] = {b1.x,b1.y,b1.z,b1.w};
            #pragma unroll
            for (int i=0;i<4;i++)
                #pragma unroll
                for (int j=0;j<4;j++)
                    acc[i][j] = fmaf(ar[i], br[j], acc[i][j]);
        }
    }

    int c0 = tx << 2;
    if (c0 >= N) return;
    #pragma unroll
    for (int i=0;i<4;i++){
        int r = row0 + (ty<<2) + i;
        if (r >= MROWS) continue;
        float4 ov = {acc[i][0], acc[i][1], acc[i][2], acc[i][3]};
        *(float4*)&dbc[(size_t)r*N + c0] = ov;
    }
}

// ---------------- MFMA bf16 GEMM, double-buffered, 1 barrier / K-step ----------------
// CFG 0: BM=64, waves 2x2, frag 2x4 | CFG 1: BM=32, waves 1x4, frag 2x2. BN=128, BK=64.
// EPI: 0 plain f32 | 1 +bias f32 | 2 +resid f32 | 3 +resid+bias f32 | 4 dual silu(a1+b1)*(a2+b2)->bf16
__device__ __forceinline__ int swz(int row, int chunk){
    return (row << 7) + ((chunk ^ (row & 7)) << 4);
}

template<int EPI, bool WB, int CFG>
__global__ __launch_bounds__(256) void mgemm_k(
    const u16* __restrict__ A,
    const void* __restrict__ W1v, const void* __restrict__ W2v,
    const float* __restrict__ bias1, const float* __restrict__ bias2,
    float* __restrict__ Cf, u16* __restrict__ Cb,
    int M, int N, int K)
{
    constexpr int  BM   = CFG ? 32 : 64;
    constexpr int  NAR  = BM/32;
    constexpr bool DUAL = (EPI==4);
    constexpr int  ABY  = BM*128;
    constexpr int  BBY  = 128*128;
    constexpr int  FM   = 2;
    constexpr int  FN   = CFG ? 2 : 4;
    __shared__ __attribute__((aligned(16))) char sm[2*ABY + 2*BBY + (DUAL ? 2*BBY : 0)];

    const int tid = threadIdx.x;
    const int row0 = blockIdx.y * BM;
    const int col0 = blockIdx.x << 7;
    const int w = tid >> 6, lane = tid & 63;
    const int wm = CFG ? 0 : (w & 1);
    const int wn = CFG ? w : (w >> 1);
    const int lr = lane & 15, lk = lane >> 4;
    const int ar0 = tid >> 3, ac8 = tid & 7;

    const u16*   W1b = (const u16*)W1v;
    const u16*   W2b = (const u16*)W2v;
    const float* W1f = (const float*)W1v;
    const float* W2f = (const float*)W2v;

    f32x4 acc[FM][FN] = {};
    f32x4 acc2[FM][FN] = {};

    s16x8 aval[NAR];
    s16x8 bval[4], b2val[4];
    float4 bvf[8], b2vf[8];

    auto loadT = [&](int kb){
        #pragma unroll
        for (int i=0;i<NAR;i++){
            int gr = row0 + i*32 + ar0;
            if (gr < M) aval[i] = *(const s16x8*)(A + (size_t)gr*K + kb + ac8*8);
            else        aval[i] = s16x8{0,0,0,0,0,0,0,0};
        }
        if (WB){
            #pragma unroll
            for (int i=0;i<4;i++)
                bval[i] = *(const s16x8*)(W1b + (size_t)(col0 + i*32 + ar0)*K + kb + ac8*8);
            if (DUAL){
                #pragma unroll
                for (int i=0;i<4;i++)
                    b2val[i] = *(const s16x8*)(W2b + (size_t)(col0 + i*32 + ar0)*K + kb + ac8*8);
            }
        } else {
            #pragma unroll
            for (int i=0;i<8;i++){
                int s = i*256 + tid;
                int r = s >> 4, q = s & 15;
                bvf[i] = *(const float4*)(W1f + (size_t)(col0 + r)*K + kb + q*4);
            }
            if (DUAL){
                #pragma unroll
                for (int i=0;i<8;i++){
                    int s = i*256 + tid;
                    int r = s >> 4, q = s & 15;
                    b2vf[i] = *(const float4*)(W2f + (size_t)(col0 + r)*K + kb + q*4);
                }
            }
        }
    };

    auto writeT = [&](char* bA, char* bB, char* bB2){
        #pragma unroll
        for (int i=0;i<NAR;i++)
            *(s16x8*)(bA + swz(i*32 + ar0, ac8)) = aval[i];
        if (WB){
            #pragma unroll
            for (int i=0;i<4;i++)
                *(s16x8*)(bB + swz(i*32 + ar0, ac8)) = bval[i];
            if (DUAL){
                #pragma unroll
                for (int i=0;i<4;i++)
                    *(s16x8*)(bB2 + swz(i*32 + ar0, ac8)) = b2val[i];
            }
        } else {
            #pragma unroll
            for (int i=0;i<8;i++){
                int s = i*256 + tid;
                int r = s >> 4, q = s & 15;
                float4 v = bvf[i];
                s16x4 cv = { (short)f2bf(v.x), (short)f2bf(v.y), (short)f2bf(v.z), (short)f2bf(v.w) };
                int off = (r << 7) + (((q >> 1) ^ (r & 7)) << 4) + ((q & 1) << 3);
                *(s16x4*)(bB + off) = cv;
            }
            if (DUAL){
                #pragma unroll
                for (int i=0;i<8;i++){
                    int s = i*256 + tid;
                    int r = s >> 4, q = s & 15;
                    float4 v = b2vf[i];
                    s16x4 cv = { (short)f2bf(v.x), (short)f2bf(v.y), (short)f2bf(v.z), (short)f2bf(v.w) };
                    int off = (r << 7) + (((q >> 1) ^ (r & 7)) << 4) + ((q & 1) << 3);
                    *(s16x4*)(bB2 + off) = cv;
                }
            }
        }
    };

    auto compute = [&](char* cA, char* cB, char* cB2){
        #pragma unroll
        for (int ks=0; ks<2; ks++){
            s16x8 af[FM], bfr[FN];
            #pragma unroll
            for (int m=0;m<FM;m++)
                af[m] = *(const s16x8*)(cA + swz(wm*32 + m*16 + lr, ks*4 + lk));
            #pragma unroll
            for (int n=0;n<FN;n++)
                bfr[n] = *(const s16x8*)(cB + swz(wn*(FN*16) + n*16 + lr, ks*4 + lk));
            #pragma unroll
            for (int m=0;m<FM;m++)
                #pragma unroll
                for (int n=0;n<FN;n++)
                    acc[m][n] = mfma_bf16(af[m], bfr[n], acc[m][n]);
            if (DUAL){
                s16x8 b2r[FN];
                #pragma unroll
                for (int n=0;n<FN;n++)
                    b2r[n] = *(const s16x8*)(cB2 + swz(wn*(FN*16) + n*16 + lr, ks*4 + lk));
                #pragma unroll
                for (int m=0;m<FM;m++)
                    #pragma unroll
                    for (int n=0;n<FN;n++)
                        acc2[m][n] = mfma_bf16(af[m], b2r[n], acc2[m][n]);
            }
        }
    };

    char* A0 = sm;          char* A1 = sm + ABY;
    char* B0 = sm + 2*ABY;  char* B1 = B0 + BBY;
    char* C0 = B1 + BBY;    char* C1 = C0 + BBY;   // dereferenced only when DUAL

    const int nkt = K >> 6;
    loadT(0);
    writeT(A0, B0, C0);
    __syncthreads();
    for (int kt=0; kt<nkt; kt++){
        const bool more = (kt+1 < nkt);
        if (more) loadT((kt+1) << 6);
        if (kt & 1){
            compute(A1, B1, C1);
            if (more) writeT(A0, B0, C0);
        } else {
            compute(A0, B0, C0);
            if (more) writeT(A1, B1, C1);
        }
        __syncthreads();
    }

    // ---- epilogue
    #pragma unroll
    for (int n=0;n<FN;n++){
        int gc = col0 + wn*(FN*16) + n*16 + lr;
        float b1 = 0.f, b2 = 0.f;
        if (EPI==1||EPI==3||EPI==4) b1 = bias1[gc];
        if (EPI==4) b2 = bias2[gc];
        #pragma unroll
        for (int m=0;m<FM;m++){
            #pragma unroll
            for (int r=0;r<4;r++){
                int gr = row0 + wm*32 + m*16 + lk*4 + r;
                if (gr >= M) continue;
                float v = acc[m][n][r];
                if (EPI==1||EPI==3) v += b1;
                if (EPI==2||EPI==3) v += Cf[(size_t)gr*N + gc];
                if (EPI==4){
                    float v1 = v + b1;
                    float v2 = acc2[m][n][r] + b2;
                    Cb[(size_t)gr*N + gc] = f2bf(v1 * sigmoidf_(v1) * v2);
                } else {
                    Cf[(size_t)gr*N + gc] = v;
                }
            }
        }
    }
}

// ---------------- fp32 -> bf16 weight conversion ----------------
__global__ void cvtw_k(const float* __restrict__ s, u16* __restrict__ d, int n)
{
    int i = blockIdx.x*blockDim.x + threadIdx.x;
    int idx = i*4;
    if (idx + 4 <= n){
        float4 v = *(const float4*)(s + idx);
        s16x4 cv = { (short)f2bf(v.x), (short)f2bf(v.y), (short)f2bf(v.z), (short)f2bf(v.w) };
        *(s16x4*)(d + idx) = cv;
    } else {
        for (int j=idx;j<n;j++) d[j] = f2bf(s[j]);
    }
}

// ---------------- Scan phase A (dt_proj fused) ----------------
__global__ __launch_bounds__(384) void scanA_k(
    const float* __restrict__ dbc, const float* __restrict__ xa,
    const float* __restrict__ dtw, const float* __restrict__ dtb,
    const float* __restrict__ a_log,
    float* __restrict__ Pout, float* __restrict__ Sout)
{
    int b = blockIdx.x / NCH;
    int c = blockIdx.x % NCH;
    int d = threadIdx.x;
    __shared__ float Ds[CHL][56];
    for (int t = threadIdx.x; t < CHL*56; t += 384){
        int j = t/56, q = t%56;
        Ds[j][q] = dbc[(size_t)(b*LL + c*CHL + j)*56 + q];
    }
    __syncthreads();
    float dtwr[RRANK];
    #pragma unroll
    for (int r=0;r<RRANK;r++) dtwr[r] = dtw[d*RRANK + r];
    float dtbv = dtb[d];
    float Aa[NST];
    #pragma unroll
    for (int n=0;n<NST;n++) Aa[n] = -__expf(a_log[d*NST+n]);
    float hst[NST], P[NST];
    #pragma unroll
    for (int n=0;n<NST;n++){ hst[n]=0.f; P[n]=1.f; }
    for (int j=0;j<CHL;j++){
        int row = b*LL + c*CHL + j;
        float t = dtbv;
        #pragma unroll
        for (int r=0;r<RRANK;r++) t = fmaf(dtwr[r], Ds[j][r], t);
        float dtv = (t > 20.f) ? t : log1pf(__expf(t));
        float xv  = xa[(size_t)row*DD + d];
        float du = dtv*xv;
        #pragma unroll
        for (int n=0;n<NST;n++){
            float e = __expf(dtv*Aa[n]);
            hst[n] = fmaf(hst[n], e, du*Ds[j][24+n]);
            P[n] *= e;
        }
    }
    size_t base = ((size_t)(b*NCH + c)*DD + d)*NST;
    #pragma unroll
    for (int n=0;n<NST;n++){ Pout[base+n]=P[n]; Sout[base+n]=hst[n]; }
}

// ---------------- Scan phase B ----------------
__global__ void scanB_k(const float* __restrict__ P, const float* __restrict__ S,
                        float* __restrict__ Hin)
{
    int idx = blockIdx.x*blockDim.x + threadIdx.x;
    if (idx >= BB*DD) return;
    int b = idx / DD, d = idx % DD;
    float h[NST];
    #pragma unroll
    for (int n=0;n<NST;n++) h[n]=0.f;
    for (int c=0;c<NCH;c++){
        size_t base = ((size_t)(b*NCH + c)*DD + d)*NST;
        #pragma unroll
        for (int n=0;n<NST;n++){
            Hin[base+n] = h[n];
            h[n] = fmaf(P[base+n], h[n], S[base+n]);
        }
    }
}

// ---------------- Scan phase C (dt_proj fused) + D_skip + SiLU(z) gate -> bf16 yg ----------------
__global__ __launch_bounds__(384) void scanC_k(
    const float* __restrict__ dbc, const float* __restrict__ xa,
    const float* __restrict__ dtw, const float* __restrict__ dtb,
    const float* __restrict__ a_log, const float* __restrict__ Hin,
    const float* __restrict__ xz, const float* __restrict__ dskip,
    u16* __restrict__ yg)
{
    int b = blockIdx.x / NCH;
    int c = blockIdx.x % NCH;
    int d = threadIdx.x;
    __shared__ float Ds[CHL][56];
    for (int t = threadIdx.x; t < CHL*56; t += 384){
        int j = t/56, q = t%56;
        Ds[j][q] = dbc[(size_t)(b*LL + c*CHL + j)*56 + q];
    }
    __syncthreads();
    float dtwr[RRANK];
    #pragma unroll
    for (int r=0;r<RRANK;r++) dtwr[r] = dtw[d*RRANK + r];
    float dtbv = dtb[d];
    float Aa[NST];
    #pragma unroll
    for (int n=0;n<NST;n++) Aa[n] = -__expf(a_log[d*NST+n]);
    float hst[NST];
    size_t hb = ((size_t)(b*NCH + c)*DD + d)*NST;
    #pragma unroll
    for (int n=0;n<NST;n++) hst[n] = Hin[hb+n];
    float dsk = dskip[d];
    for (int j=0;j<CHL;j++){
        int row = b*LL + c*CHL + j;
        float t = dtbv;
        #pragma unroll
        for (int r=0;r<RRANK;r++) t = fmaf(dtwr[r], Ds[j][r], t);
        float dtv = (t > 20.f) ? t : log1pf(__expf(t));
        float xv  = xa[(size_t)row*DD + d];
        float du = dtv*xv;
        float y = 0.f;
        #pragma unroll
        for (int n=0;n<NST;n++){
            float e = __expf(dtv*Aa[n]);
            hst[n] = fmaf(hst[n], e, du*Ds[j][24+n]);
            y = fmaf(hst[n], Ds[j][40+n], y);
        }
        float zv = xz[(size_t)row*768 + 384 + d];
        float g = zv * sigmoidf_(zv);
        yg[(size_t)row*DD + d] = f2bf((y + dsk*xv)*g);
    }
}

// ---------------- host-side MFMA launcher (WB gating) ----------------
template<int EPI, int CFG>
static void mg(bool wb, dim3 g, hipStream_t s, const void* A,
               const void* Wb, const void* Wf, const void* W2b, const void* W2f,
               const float* b1, const float* b2, float* Cf, u16* Cb,
               int M, int N, int K)
{
    if (wb) mgemm_k<EPI,true ,CFG><<<g,256,0,s>>>((const u16*)A, Wb, W2b, b1, b2, Cf, Cb, M, N, K);
    else    mgemm_k<EPI,false,CFG><<<g,256,0,s>>>((const u16*)A, Wf, W2f, b1, b2, Cf, Cb, M, N, K);
}

extern "C" void kernel_launch(void* const* d_in, const int* in_sizes, int n_in,
                              void* d_out, int out_size, void* d_ws, size_t ws_size,
                              hipStream_t stream)
{
    const float* x         = (const float*)d_in[0];
    const float* patch_w   = (const float*)d_in[1];
    const float* patch_b   = (const float*)d_in[2];
    const float* norm1_w   = (const float*)d_in[3];
    const float* norm1_b   = (const float*)d_in[4];
    const float* in_proj_w = (const float*)d_in[5];
    const float* conv_w    = (const float*)d_in[6];
    const float* conv_b    = (const float*)d_in[7];
    const float* x_proj_w  = (const float*)d_in[8];
    const float* dt_w      = (const float*)d_in[9];
    const float* dt_b      = (const float*)d_in[10];
    const float* A_log     = (const float*)d_in[11];
    const float* D_skip    = (const float*)d_in[12];
    const float* out_w     = (const float*)d_in[13];
    const float* norm2_w   = (const float*)d_in[14];
    const float* norm2_b   = (const float*)d_in[15];
    const float* w1_w      = (const float*)d_in[16];
    const float* w1_b      = (const float*)d_in[17];
    const float* w2_w      = (const float*)d_in[18];
    const float* w2_b      = (const float*)d_in[19];
    const float* w3_w      = (const float*)d_in[20];
    const float* w3_b      = (const float*)d_in[21];
    const float* normf_w   = (const float*)d_in[22];
    const float* normf_b   = (const float*)d_in[23];

    char* wsb = (char*)d_ws;
    size_t o = 0;
    auto take = [&](size_t bytes) -> char* {
        char* p = wsb + o;
        o += (bytes + 255) & ~(size_t)255;
        return p;
    };

    float* h    = (float*)take((size_t)602112*4);
    float* xz   = (float*)take((size_t)1204224*4);
    float* xa   = (float*)take((size_t)602112*4);
    float* dbc  = (float*)take((size_t)87808*4);
    float* Pb   = (float*)take((size_t)688128*4);
    float* Sb   = (float*)take((size_t)688128*4);
    float* Hi   = (float*)take((size_t)688128*4);
    u16*  xn    = (u16*)take((size_t)602112*2);
    u16*  yg    = (u16*)take((size_t)602112*2);
    u16*  hid   = (u16*)take((size_t)1605632*2);
    u16*  patches = hid;   // alias: consumed before hid is produced

    const size_t NPW = 294912, NIN = 7077888, NOUT = 3538944, NW1 = 9437184, NW2 = 9437184, NW3 = 9437184;
    u16* wcP = (u16*)take(NPW*2);
    u16* wcI = (u16*)take(NIN*2);
    u16* wcO = (u16*)take(NOUT*2);
    u16* wc1 = (u16*)take(NW1*2);
    u16* wc2 = (u16*)take(NW2*2);
    u16* wc3 = (u16*)take(NW3*2);
    bool wb = (ws_size >= o);

    if (wb){
        cvtw_k<<<(int)((NPW/4+255)/256), 256, 0, stream>>>(patch_w, wcP, (int)NPW);
        cvtw_k<<<(int)((NIN/4+255)/256), 256, 0, stream>>>(in_proj_w, wcI, (int)NIN);
        cvtw_k<<<(int)((NOUT/4+255)/256),256, 0, stream>>>(out_w, wcO, (int)NOUT);
        cvtw_k<<<(int)((NW1/4+255)/256), 256, 0, stream>>>(w1_w, wc1, (int)NW1);
        cvtw_k<<<(int)((NW2/4+255)/256), 256, 0, stream>>>(w2_w, wc2, (int)NW2);
        cvtw_k<<<(int)((NW3/4+255)/256), 256, 0, stream>>>(w3_w, wc3, (int)NW3);
    }

    const int GY64 = (MROWS + 63)/64;   // 25
    const int GY32 = (MROWS + 31)/32;   // 49

    // Patch embedding
    gather_k<<<(MROWS*768+255)/256, 256, 0, stream>>>(x, patches);
    mg<1,1>(wb, dim3(3,GY32), stream, patches, wcP, patch_w, nullptr, nullptr,
            patch_b, nullptr, h, nullptr, MROWS, DD, 768);

    for (int i=0;i<NDEPTH;i++){
        ln_k<1><<<MROWS, 64, 0, stream>>>(h, norm1_w + i*DD, norm1_b + i*DD, xn);
        mg<0,0>(wb, dim3(6,GY64), stream, xn, wcI + (size_t)i*768*DD, in_proj_w + (size_t)i*768*DD,
                nullptr, nullptr, nullptr, nullptr, xz, nullptr, MROWS, 768, DD);
        xprojconv_k<<<dim3(1,GY64), 256, 0, stream>>>(xz, conv_w + i*DD*4, conv_b + i*DD,
                                                      x_proj_w + (size_t)i*56*DD, xa, dbc);
        scanA_k<<<BB*NCH, 384, 0, stream>>>(dbc, xa, dt_w + (size_t)i*DD*RRANK, dt_b + i*DD,
                                            A_log + (size_t)i*DD*NST, Pb, Sb);
        scanB_k<<<(BB*DD+255)/256, 256, 0, stream>>>(Pb, Sb, Hi);
        scanC_k<<<BB*NCH, 384, 0, stream>>>(dbc, xa, dt_w + (size_t)i*DD*RRANK, dt_b + i*DD,
                                            A_log + (size_t)i*DD*NST, Hi, xz, D_skip + i*DD, yg);
        mg<2,1>(wb, dim3(3,GY32), stream, yg, wcO + (size_t)i*DD*DD, out_w + (size_t)i*DD*DD,
                nullptr, nullptr, nullptr, nullptr, h, nullptr, MROWS, DD, DD);
        ln_k<1><<<MROWS, 64, 0, stream>>>(h, norm2_w + i*DD, norm2_b + i*DD, xn);
        mg<4,0>(wb, dim3(8,GY64), stream, xn,
                wc1 + (size_t)i*HHID*DD, w1_w + (size_t)i*HHID*DD,
                wc2 + (size_t)i*HHID*DD, w2_w + (size_t)i*HHID*DD,
                w1_b + i*HHID, w2_b + i*HHID, nullptr, hid, MROWS, HHID, DD);
        mg<3,1>(wb, dim3(3,GY32), stream, hid, wc3 + (size_t)i*DD*HHID, w3_w + (size_t)i*DD*HHID,
                nullptr, nullptr, w3_b + i*DD, nullptr, h, nullptr, MROWS, DD, HHID);
    }

    ln_k<0><<<MROWS, 64, 0, stream>>>(h, normf_w, normf_b, d_out);
}

// Round 4
// 2772.547 us; speedup vs baseline: 1.7053x; 1.7053x over previous
//
#include <hip/hip_runtime.h>
#include <math.h>

#define BB 8
#define LL 196
#define DD 384
#define NDEPTH 24
#define NST 16
#define RRANK 24
#define HHID 1024
#define MROWS (BB*LL)   /* 1568 */
#define NCH 14
#define CHL 14

typedef float f32x4 __attribute__((ext_vector_type(4)));
typedef short s16x8 __attribute__((ext_vector_type(8)));
typedef short s16x4 __attribute__((ext_vector_type(4)));
typedef __bf16 b16x8 __attribute__((ext_vector_type(8)));
typedef unsigned short u16;
typedef unsigned int u32;

__device__ __forceinline__ float sigmoidf_(float x){ return 1.f/(1.f+__expf(-x)); }

__device__ __forceinline__ u16 f2bf(float f){
    u32 u = __builtin_bit_cast(u32, f);
    u32 r = (u + 0x7fffu + ((u >> 16) & 1u)) >> 16;   // RNE
    return (u16)r;
}

// ---- MFMA wrapper: SFINAE hedge over builtin operand type ----
template<typename V>
__device__ __forceinline__ auto mfma_try(V a, V b, f32x4 c, int)
    -> decltype(__builtin_amdgcn_mfma_f32_16x16x32_bf16(a, b, c, 0, 0, 0))
{ return __builtin_amdgcn_mfma_f32_16x16x32_bf16(a, b, c, 0, 0, 0); }

template<typename V>
__device__ __forceinline__ f32x4 mfma_try(V a, V b, f32x4 c, long)
{
    return __builtin_amdgcn_mfma_f32_16x16x32_bf16(
        __builtin_bit_cast(b16x8, a), __builtin_bit_cast(b16x8, b), c, 0, 0, 0);
}
__device__ __forceinline__ f32x4 mfma_bf16(s16x8 a, s16x8 b, f32x4 c){ return mfma_try(a, b, c, 0); }

// ---------------- LayerNorm: BF=1 -> bf16 out, BF=0 -> f32 out ----------------
template<int BF>
__global__ __launch_bounds__(64) void ln_k(const float* __restrict__ X,
    const float* __restrict__ w, const float* __restrict__ b, void* __restrict__ Yv)
{
    int row = blockIdx.x;
    int lane = threadIdx.x;
    const float* x = X + (size_t)row*DD;
    float v[6]; float s=0.f, s2=0.f;
    #pragma unroll
    for (int j=0;j<6;j++){ float t = x[lane + j*64]; v[j]=t; s+=t; s2+=t*t; }
    #pragma unroll
    for (int o=32;o>=1;o>>=1){ s += __shfl_xor(s,o); s2 += __shfl_xor(s2,o); }
    float m = s*(1.f/DD);
    float var = s2*(1.f/DD) - m*m;
    float rstd = rsqrtf(var + 1e-5f);
    #pragma unroll
    for (int j=0;j<6;j++){
        int c = lane + j*64;
        float val = (v[j]-m)*rstd*w[c] + b[c];
        if (BF) ((u16*)Yv)[(size_t)row*DD + c] = f2bf(val);
        else    ((float*)Yv)[(size_t)row*DD + c] = val;
    }
}

// ---------------- Patch gather -> bf16 (B*L, 768) ----------------
__global__ void gather_k(const float* __restrict__ x, u16* __restrict__ P)
{
    int idx = blockIdx.x*blockDim.x + threadIdx.x;
    if (idx >= MROWS*768) return;
    int k = idx % 768;
    int bl = idx / 768;
    int l = bl % LL;
    int b = bl / LL;
    int c = k >> 8;
    int rem = k & 255;
    int dy = rem >> 4, dx = rem & 15;
    int py = l / 14, px = l % 14;
    P[idx] = f2bf(x[(((size_t)b*3 + c)*224 + (py*16+dy))*224 + (px*16+dx)]);
}

// ---------------- Causal depthwise conv (K=4) + SiLU -> xa f32 + xab bf16 ----------------
__global__ void conv_silu_k(const float* __restrict__ xz,
    const float* __restrict__ cw, const float* __restrict__ cb,
    float* __restrict__ xa, u16* __restrict__ xab)
{
    int idx = blockIdx.x*blockDim.x + threadIdx.x;
    if (idx >= MROWS*DD) return;
    int d = idx % DD;
    int bl = idx / DD;
    int l = bl % LL;
    int b = bl / LL;
    float acc = cb[d];
    #pragma unroll
    for (int k=0;k<4;k++){
        int ls = l + k - 3;
        if (ls >= 0) acc = fmaf(xz[(size_t)(b*LL+ls)*768 + d], cw[d*4+k], acc);
    }
    float v = acc * sigmoidf_(acc);
    xa[idx] = v;
    xab[idx] = f2bf(v);
}

// ---------------- small fp32 GEMM fallback (x_proj when !wb) ----------------
template<int EPI>
__global__ __launch_bounds__(256) void gemm_k(
    const float* __restrict__ A, int lda,
    const float* __restrict__ W,
    const float* __restrict__ bias,
    float* __restrict__ C,
    int M, int N, int K)
{
    __shared__ float As[16][68];
    __shared__ float Ws1[16][68];

    int tid = threadIdx.x;
    int tx = tid & 15, ty = tid >> 4;
    int row0 = blockIdx.y*64, col0 = blockIdx.x*64;

    int ldr  = tid >> 2;
    int ldk4 = (tid & 3) << 2;

    float acc[4][4] = {{0.f}};

    const float* Arow  = A + (size_t)(row0+ldr)*lda;
    const float* Wrow  = W + (size_t)(col0+ldr)*K;
    bool aok = (row0+ldr) < M;
    bool wok = (col0+ldr) < N;

    int KT = (K+15) >> 4;
    for (int kt=0; kt<KT; kt++){
        int kg = kt*16 + ldk4;
        float4 av = {0,0,0,0}, wv = {0,0,0,0};
        if (aok && kg+4 <= K) av = *(const float4*)(Arow + kg);
        if (wok && kg+4 <= K) wv = *(const float4*)(Wrow + kg);
        __syncthreads();
        As [ldk4+0][ldr]=av.x; As [ldk4+1][ldr]=av.y; As [ldk4+2][ldr]=av.z; As [ldk4+3][ldr]=av.w;
        Ws1[ldk4+0][ldr]=wv.x; Ws1[ldk4+1][ldr]=wv.y; Ws1[ldk4+2][ldr]=wv.z; Ws1[ldk4+3][ldr]=wv.w;
        __syncthreads();
        #pragma unroll
        for (int k=0;k<16;k++){
            const float4 a  = *(const float4*)&As[k][ty<<2];
            const float4 b1 = *(const float4*)&Ws1[k][tx<<2];
            float ar[4] = {a.x,a.y,a.z,a.w};
            float br[4] = {b1.x,b1.y,b1.z,b1.w};
            #pragma unroll
            for (int i=0;i<4;i++)
                #pragma unroll
                for (int j=0;j<4;j++)
                    acc[i][j] = fmaf(ar[i], br[j], acc[i][j]);
        }
    }

    int c0 = col0 + (tx<<2);
    #pragma unroll
    for (int i=0;i<4;i++){
        int r = row0 + (ty<<2) + i;
        if (r >= M) continue;
        #pragma unroll
        for (int j=0;j<4;j++){
            if (c0+j < N) C[(size_t)r*N + c0 + j] = acc[i][j];
        }
    }
}

// ---------------- MFMA bf16 GEMM, double-buffered, 1 barrier / K-step ----------------
// CFG 0: BM=64, waves 2x2, frag 2x4 | CFG 1: BM=32, waves 1x4, frag 2x2. BN=128, BK=64.
// EPI: 0 plain f32 | 1 +bias f32 | 2 +resid f32 | 3 +resid+bias f32 | 4 dual silu(a1+b1)*(a2+b2)->bf16
__device__ __forceinline__ int swz(int row, int chunk){
    return (row << 7) + ((chunk ^ (row & 7)) << 4);
}

template<int EPI, bool WB, int CFG>
__global__ __launch_bounds__(256) void mgemm_k(
    const u16* __restrict__ A,
    const void* __restrict__ W1v, const void* __restrict__ W2v,
    const float* __restrict__ bias1, const float* __restrict__ bias2,
    float* __restrict__ Cf, u16* __restrict__ Cb,
    int M, int N, int K)
{
    constexpr int  BM   = CFG ? 32 : 64;
    constexpr int  NAR  = BM/32;
    constexpr bool DUAL = (EPI==4);
    constexpr int  ABY  = BM*128;
    constexpr int  BBY  = 128*128;
    constexpr int  FM   = 2;
    constexpr int  FN   = CFG ? 2 : 4;
    __shared__ __attribute__((aligned(16))) char sm[2*ABY + 2*BBY + (DUAL ? 2*BBY : 0)];

    const int tid = threadIdx.x;
    const int row0 = blockIdx.y * BM;
    const int col0 = blockIdx.x << 7;
    const int w = tid >> 6, lane = tid & 63;
    const int wm = CFG ? 0 : (w & 1);
    const int wn = CFG ? w : (w >> 1);
    const int lr = lane & 15, lk = lane >> 4;
    const int ar0 = tid >> 3, ac8 = tid & 7;

    const u16*   W1b = (const u16*)W1v;
    const u16*   W2b = (const u16*)W2v;
    const float* W1f = (const float*)W1v;
    const float* W2f = (const float*)W2v;

    f32x4 acc[FM][FN] = {};
    f32x4 acc2[FM][FN] = {};

    s16x8 aval[NAR];
    s16x8 bval[4], b2val[4];
    float4 bvf[8], b2vf[8];

    auto loadT = [&](int kb){
        #pragma unroll
        for (int i=0;i<NAR;i++){
            int gr = row0 + i*32 + ar0;
            if (gr < M) aval[i] = *(const s16x8*)(A + (size_t)gr*K + kb + ac8*8);
            else        aval[i] = s16x8{0,0,0,0,0,0,0,0};
        }
        if (WB){
            #pragma unroll
            for (int i=0;i<4;i++)
                bval[i] = *(const s16x8*)(W1b + (size_t)(col0 + i*32 + ar0)*K + kb + ac8*8);
            if (DUAL){
                #pragma unroll
                for (int i=0;i<4;i++)
                    b2val[i] = *(const s16x8*)(W2b + (size_t)(col0 + i*32 + ar0)*K + kb + ac8*8);
            }
        } else {
            #pragma unroll
            for (int i=0;i<8;i++){
                int s = i*256 + tid;
                int r = s >> 4, q = s & 15;
                bvf[i] = *(const float4*)(W1f + (size_t)(col0 + r)*K + kb + q*4);
            }
            if (DUAL){
                #pragma unroll
                for (int i=0;i<8;i++){
                    int s = i*256 + tid;
                    int r = s >> 4, q = s & 15;
                    b2vf[i] = *(const float4*)(W2f + (size_t)(col0 + r)*K + kb + q*4);
                }
            }
        }
    };

    auto writeT = [&](char* bA, char* bB, char* bB2){
        #pragma unroll
        for (int i=0;i<NAR;i++)
            *(s16x8*)(bA + swz(i*32 + ar0, ac8)) = aval[i];
        if (WB){
            #pragma unroll
            for (int i=0;i<4;i++)
                *(s16x8*)(bB + swz(i*32 + ar0, ac8)) = bval[i];
            if (DUAL){
                #pragma unroll
                for (int i=0;i<4;i++)
                    *(s16x8*)(bB2 + swz(i*32 + ar0, ac8)) = b2val[i];
            }
        } else {
            #pragma unroll
            for (int i=0;i<8;i++){
                int s = i*256 + tid;
                int r = s >> 4, q = s & 15;
                float4 v = bvf[i];
                s16x4 cv = { (short)f2bf(v.x), (short)f2bf(v.y), (short)f2bf(v.z), (short)f2bf(v.w) };
                int off = (r << 7) + (((q >> 1) ^ (r & 7)) << 4) + ((q & 1) << 3);
                *(s16x4*)(bB + off) = cv;
            }
            if (DUAL){
                #pragma unroll
                for (int i=0;i<8;i++){
                    int s = i*256 + tid;
                    int r = s >> 4, q = s & 15;
                    float4 v = b2vf[i];
                    s16x4 cv = { (short)f2bf(v.x), (short)f2bf(v.y), (short)f2bf(v.z), (short)f2bf(v.w) };
                    int off = (r << 7) + (((q >> 1) ^ (r & 7)) << 4) + ((q & 1) << 3);
                    *(s16x4*)(bB2 + off) = cv;
                }
            }
        }
    };

    auto compute = [&](char* cA, char* cB, char* cB2){
        #pragma unroll
        for (int ks=0; ks<2; ks++){
            s16x8 af[FM], bfr[FN];
            #pragma unroll
            for (int m=0;m<FM;m++)
                af[m] = *(const s16x8*)(cA + swz(wm*32 + m*16 + lr, ks*4 + lk));
            #pragma unroll
            for (int n=0;n<FN;n++)
                bfr[n] = *(const s16x8*)(cB + swz(wn*(FN*16) + n*16 + lr, ks*4 + lk));
            #pragma unroll
            for (int m=0;m<FM;m++)
                #pragma unroll
                for (int n=0;n<FN;n++)
                    acc[m][n] = mfma_bf16(af[m], bfr[n], acc[m][n]);
            if (DUAL){
                s16x8 b2r[FN];
                #pragma unroll
                for (int n=0;n<FN;n++)
                    b2r[n] = *(const s16x8*)(cB2 + swz(wn*(FN*16) + n*16 + lr, ks*4 + lk));
                #pragma unroll
                for (int m=0;m<FM;m++)
                    #pragma unroll
                    for (int n=0;n<FN;n++)
                        acc2[m][n] = mfma_bf16(af[m], b2r[n], acc2[m][n]);
            }
        }
    };

    char* A0 = sm;          char* A1 = sm + ABY;
    char* B0 = sm + 2*ABY;  char* B1 = B0 + BBY;
    char* C0 = B1 + BBY;    char* C1 = C0 + BBY;   // dereferenced only when DUAL

    const int nkt = K >> 6;
    loadT(0);
    writeT(A0, B0, C0);
    __syncthreads();
    for (int kt=0; kt<nkt; kt++){
        const bool more = (kt+1 < nkt);
        if (more) loadT((kt+1) << 6);
        if (kt & 1){
            compute(A1, B1, C1);
            if (more) writeT(A0, B0, C0);
        } else {
            compute(A0, B0, C0);
            if (more) writeT(A1, B1, C1);
        }
        __syncthreads();
    }

    // ---- epilogue
    #pragma unroll
    for (int n=0;n<FN;n++){
        int gc = col0 + wn*(FN*16) + n*16 + lr;
        if (gc >= N) continue;
        float b1 = 0.f, b2 = 0.f;
        if (EPI==1||EPI==3||EPI==4) b1 = bias1[gc];
        if (EPI==4) b2 = bias2[gc];
        #pragma unroll
        for (int m=0;m<FM;m++){
            #pragma unroll
            for (int r=0;r<4;r++){
                int gr = row0 + wm*32 + m*16 + lk*4 + r;
                if (gr >= M) continue;
                float v = acc[m][n][r];
                if (EPI==1||EPI==3) v += b1;
                if (EPI==2||EPI==3) v += Cf[(size_t)gr*N + gc];
                if (EPI==4){
                    float v1 = v + b1;
                    float v2 = acc2[m][n][r] + b2;
                    Cb[(size_t)gr*N + gc] = f2bf(v1 * sigmoidf_(v1) * v2);
                } else {
                    Cf[(size_t)gr*N + gc] = v;
                }
            }
        }
    }
}

// ---------------- fp32 -> bf16 weight conversion ----------------
__global__ void cvtw_k(const float* __restrict__ s, u16* __restrict__ d, int n)
{
    int i = blockIdx.x*blockDim.x + threadIdx.x;
    int idx = i*4;
    if (idx + 4 <= n){
        float4 v = *(const float4*)(s + idx);
        s16x4 cv = { (short)f2bf(v.x), (short)f2bf(v.y), (short)f2bf(v.z), (short)f2bf(v.w) };
        *(s16x4*)(d + idx) = cv;
    } else {
        for (int j=idx;j<n;j++) d[j] = f2bf(s[j]);
    }
}

// ---------------- x_proj weight: (24,56,384) f32 -> (24,128,384) bf16 zero-padded ----------------
__global__ void cvtpad_k(const float* __restrict__ s, u16* __restrict__ d)
{
    int i = blockIdx.x*blockDim.x + threadIdx.x;
    if (i >= NDEPTH*128*384) return;
    int k = i % 384;
    int r = (i/384) % 128;
    int L = i/(384*128);
    float v = (r < 56) ? s[((size_t)L*56 + r)*384 + k] : 0.f;
    d[i] = f2bf(v);
}

// ---------------- Scan phase A (dt_proj fused) ----------------
__global__ __launch_bounds__(384) void scanA_k(
    const float* __restrict__ dbc, const float* __restrict__ xa,
    const float* __restrict__ dtw, const float* __restrict__ dtb,
    const float* __restrict__ a_log,
    float* __restrict__ Pout, float* __restrict__ Sout)
{
    int b = blockIdx.x / NCH;
    int c = blockIdx.x % NCH;
    int d = threadIdx.x;
    __shared__ float Ds[CHL][56];
    for (int t = threadIdx.x; t < CHL*56; t += 384){
        int j = t/56, q = t%56;
        Ds[j][q] = dbc[(size_t)(b*LL + c*CHL + j)*56 + q];
    }
    __syncthreads();
    float dtwr[RRANK];
    #pragma unroll
    for (int r=0;r<RRANK;r++) dtwr[r] = dtw[d*RRANK + r];
    float dtbv = dtb[d];
    float Aa[NST];
    #pragma unroll
    for (int n=0;n<NST;n++) Aa[n] = -__expf(a_log[d*NST+n]);
    float hst[NST], P[NST];
    #pragma unroll
    for (int n=0;n<NST;n++){ hst[n]=0.f; P[n]=1.f; }
    for (int j=0;j<CHL;j++){
        int row = b*LL + c*CHL + j;
        float t = dtbv;
        #pragma unroll
        for (int r=0;r<RRANK;r++) t = fmaf(dtwr[r], Ds[j][r], t);
        float dtv = (t > 20.f) ? t : log1pf(__expf(t));
        float xv  = xa[(size_t)row*DD + d];
        float du = dtv*xv;
        #pragma unroll
        for (int n=0;n<NST;n++){
            float e = __expf(dtv*Aa[n]);
            hst[n] = fmaf(hst[n], e, du*Ds[j][24+n]);
            P[n] *= e;
        }
    }
    size_t base = ((size_t)(b*NCH + c)*DD + d)*NST;
    #pragma unroll
    for (int n=0;n<NST;n++){ Pout[base+n]=P[n]; Sout[base+n]=hst[n]; }
}

// ---------------- Scan phase B ----------------
__global__ void scanB_k(const float* __restrict__ P, const float* __restrict__ S,
                        float* __restrict__ Hin)
{
    int idx = blockIdx.x*blockDim.x + threadIdx.x;
    if (idx >= BB*DD) return;
    int b = idx / DD, d = idx % DD;
    float h[NST];
    #pragma unroll
    for (int n=0;n<NST;n++) h[n]=0.f;
    for (int c=0;c<NCH;c++){
        size_t base = ((size_t)(b*NCH + c)*DD + d)*NST;
        #pragma unroll
        for (int n=0;n<NST;n++){
            Hin[base+n] = h[n];
            h[n] = fmaf(P[base+n], h[n], S[base+n]);
        }
    }
}

// ---------------- Scan phase C (dt_proj fused) + D_skip + SiLU(z) gate -> bf16 yg ----------------
__global__ __launch_bounds__(384) void scanC_k(
    const float* __restrict__ dbc, const float* __restrict__ xa,
    const float* __restrict__ dtw, const float* __restrict__ dtb,
    const float* __restrict__ a_log, const float* __restrict__ Hin,
    const float* __restrict__ xz, const float* __restrict__ dskip,
    u16* __restrict__ yg)
{
    int b = blockIdx.x / NCH;
    int c = blockIdx.x % NCH;
    int d = threadIdx.x;
    __shared__ float Ds[CHL][56];
    for (int t = threadIdx.x; t < CHL*56; t += 384){
        int j = t/56, q = t%56;
        Ds[j][q] = dbc[(size_t)(b*LL + c*CHL + j)*56 + q];
    }
    __syncthreads();
    float dtwr[RRANK];
    #pragma unroll
    for (int r=0;r<RRANK;r++) dtwr[r] = dtw[d*RRANK + r];
    float dtbv = dtb[d];
    float Aa[NST];
    #pragma unroll
    for (int n=0;n<NST;n++) Aa[n] = -__expf(a_log[d*NST+n]);
    float hst[NST];
    size_t hb = ((size_t)(b*NCH + c)*DD + d)*NST;
    #pragma unroll
    for (int n=0;n<NST;n++) hst[n] = Hin[hb+n];
    float dsk = dskip[d];
    for (int j=0;j<CHL;j++){
        int row = b*LL + c*CHL + j;
        float t = dtbv;
        #pragma unroll
        for (int r=0;r<RRANK;r++) t = fmaf(dtwr[r], Ds[j][r], t);
        float dtv = (t > 20.f) ? t : log1pf(__expf(t));
        float xv  = xa[(size_t)row*DD + d];
        float du = dtv*xv;
        float y = 0.f;
        #pragma unroll
        for (int n=0;n<NST;n++){
            float e = __expf(dtv*Aa[n]);
            hst[n] = fmaf(hst[n], e, du*Ds[j][24+n]);
            y = fmaf(hst[n], Ds[j][40+n], y);
        }
        float zv = xz[(size_t)row*768 + 384 + d];
        float g = zv * sigmoidf_(zv);
        yg[(size_t)row*DD + d] = f2bf((y + dsk*xv)*g);
    }
}

// ---------------- host-side MFMA launcher (WB gating) ----------------
template<int EPI, int CFG>
static void mg(bool wb, dim3 g, hipStream_t s, const void* A,
               const void* Wb, const void* Wf, const void* W2b, const void* W2f,
               const float* b1, const float* b2, float* Cf, u16* Cb,
               int M, int N, int K)
{
    if (wb) mgemm_k<EPI,true ,CFG><<<g,256,0,s>>>((const u16*)A, Wb, W2b, b1, b2, Cf, Cb, M, N, K);
    else    mgemm_k<EPI,false,CFG><<<g,256,0,s>>>((const u16*)A, Wf, W2f, b1, b2, Cf, Cb, M, N, K);
}

extern "C" void kernel_launch(void* const* d_in, const int* in_sizes, int n_in,
                              void* d_out, int out_size, void* d_ws, size_t ws_size,
                              hipStream_t stream)
{
    const float* x         = (const float*)d_in[0];
    const float* patch_w   = (const float*)d_in[1];
    const float* patch_b   = (const float*)d_in[2];
    const float* norm1_w   = (const float*)d_in[3];
    const float* norm1_b   = (const float*)d_in[4];
    const float* in_proj_w = (const float*)d_in[5];
    const float* conv_w    = (const float*)d_in[6];
    const float* conv_b    = (const float*)d_in[7];
    const float* x_proj_w  = (const float*)d_in[8];
    const float* dt_w      = (const float*)d_in[9];
    const float* dt_b      = (const float*)d_in[10];
    const float* A_log     = (const float*)d_in[11];
    const float* D_skip    = (const float*)d_in[12];
    const float* out_w     = (const float*)d_in[13];
    const float* norm2_w   = (const float*)d_in[14];
    const float* norm2_b   = (const float*)d_in[15];
    const float* w1_w      = (const float*)d_in[16];
    const float* w1_b      = (const float*)d_in[17];
    const float* w2_w      = (const float*)d_in[18];
    const float* w2_b      = (const float*)d_in[19];
    const float* w3_w      = (const float*)d_in[20];
    const float* w3_b      = (const float*)d_in[21];
    const float* normf_w   = (const float*)d_in[22];
    const float* normf_b   = (const float*)d_in[23];

    char* wsb = (char*)d_ws;
    size_t o = 0;
    auto take = [&](size_t bytes) -> char* {
        char* p = wsb + o;
        o += (bytes + 255) & ~(size_t)255;
        return p;
    };

    float* h    = (float*)take((size_t)602112*4);
    float* xz   = (float*)take((size_t)1204224*4);
    float* xa   = (float*)take((size_t)602112*4);
    float* dbc  = (float*)take((size_t)87808*4);
    float* Pb   = (float*)take((size_t)688128*4);
    float* Sb   = (float*)take((size_t)688128*4);
    float* Hi   = (float*)take((size_t)688128*4);
    u16*  xn    = (u16*)take((size_t)602112*2);
    u16*  xab   = (u16*)take((size_t)602112*2);
    u16*  yg    = (u16*)take((size_t)602112*2);
    u16*  hid   = (u16*)take((size_t)1605632*2);
    u16*  patches = hid;   // alias: consumed before hid is produced

    const size_t NPW = 294912, NIN = 7077888, NOUT = 3538944, NW1 = 9437184, NW2 = 9437184, NW3 = 9437184;
    const size_t NXP = (size_t)NDEPTH*128*384;   // padded x_proj cache
    u16* wcP = (u16*)take(NPW*2);
    u16* wcI = (u16*)take(NIN*2);
    u16* wcO = (u16*)take(NOUT*2);
    u16* wc1 = (u16*)take(NW1*2);
    u16* wc2 = (u16*)take(NW2*2);
    u16* wc3 = (u16*)take(NW3*2);
    u16* wcX = (u16*)take(NXP*2);
    bool wb = (ws_size >= o);

    if (wb){
        cvtw_k<<<(int)((NPW/4+255)/256), 256, 0, stream>>>(patch_w, wcP, (int)NPW);
        cvtw_k<<<(int)((NIN/4+255)/256), 256, 0, stream>>>(in_proj_w, wcI, (int)NIN);
        cvtw_k<<<(int)((NOUT/4+255)/256),256, 0, stream>>>(out_w, wcO, (int)NOUT);
        cvtw_k<<<(int)((NW1/4+255)/256), 256, 0, stream>>>(w1_w, wc1, (int)NW1);
        cvtw_k<<<(int)((NW2/4+255)/256), 256, 0, stream>>>(w2_w, wc2, (int)NW2);
        cvtw_k<<<(int)((NW3/4+255)/256), 256, 0, stream>>>(w3_w, wc3, (int)NW3);
        cvtpad_k<<<(int)((NXP+255)/256), 256, 0, stream>>>(x_proj_w, wcX);
    }

    const int GY64 = (MROWS + 63)/64;   // 25
    const int GY32 = (MROWS + 31)/32;   // 49

    // Patch embedding
    gather_k<<<(MROWS*768+255)/256, 256, 0, stream>>>(x, patches);
    mg<1,1>(wb, dim3(3,GY32), stream, patches, wcP, patch_w, nullptr, nullptr,
            patch_b, nullptr, h, nullptr, MROWS, DD, 768);

    for (int i=0;i<NDEPTH;i++){
        ln_k<1><<<MROWS, 64, 0, stream>>>(h, norm1_w + i*DD, norm1_b + i*DD, xn);
        mg<0,1>(wb, dim3(6,GY32), stream, xn, wcI + (size_t)i*768*DD, in_proj_w + (size_t)i*768*DD,
                nullptr, nullptr, nullptr, nullptr, xz, nullptr, MROWS, 768, DD);
        conv_silu_k<<<(MROWS*DD+255)/256, 256, 0, stream>>>(xz, conv_w + i*DD*4, conv_b + i*DD, xa, xab);
        if (wb){
            mgemm_k<0,true,1><<<dim3(1,GY32), 256, 0, stream>>>(
                xab, wcX + (size_t)i*128*384, nullptr, nullptr, nullptr,
                dbc, nullptr, MROWS, 56, DD);
        } else {
            gemm_k<0><<<dim3(1,GY64), 256, 0, stream>>>(xa, DD, x_proj_w + (size_t)i*56*DD,
                                                        nullptr, dbc, MROWS, 56, DD);
        }
        scanA_k<<<BB*NCH, 384, 0, stream>>>(dbc, xa, dt_w + (size_t)i*DD*RRANK, dt_b + i*DD,
                                            A_log + (size_t)i*DD*NST, Pb, Sb);
        scanB_k<<<(BB*DD+255)/256, 256, 0, stream>>>(Pb, Sb, Hi);
        scanC_k<<<BB*NCH, 384, 0, stream>>>(dbc, xa, dt_w + (size_t)i*DD*RRANK, dt_b + i*DD,
                                            A_log + (size_t)i*DD*NST, Hi, xz, D_skip + i*DD, yg);
        mg<2,1>(wb, dim3(3,GY32), stream, yg, wcO + (size_t)i*DD*DD, out_w + (size_t)i*DD*DD,
                nullptr, nullptr, nullptr, nullptr, h, nullptr, MROWS, DD, DD);
        ln_k<1><<<MROWS, 64, 0, stream>>>(h, norm2_w + i*DD, norm2_b + i*DD, xn);
        mg<4,1>(wb, dim3(8,GY32), stream, xn,
                wc1 + (size_t)i*HHID*DD, w1_w + (size_t)i*HHID*DD,
                wc2 + (size_t)i*HHID*DD, w2_w + (size_t)i*HHID*DD,
                w1_b + i*HHID, w2_b + i*HHID, nullptr, hid, MROWS, HHID, DD);
        mg<3,1>(wb, dim3(3,GY32), stream, hid, wc3 + (size_t)i*DD*HHID, w3_w + (size_t)i*DD*HHID,
                nullptr, nullptr, w3_b + i*DD, nullptr, h, nullptr, MROWS, DD, HHID);
    }

    ln_k<0><<<MROWS, 64, 0, stream>>>(h, normf_w, normf_b, d_out);
}

// Round 5
// 2619.939 us; speedup vs baseline: 1.8046x; 1.0582x over previous
//
#include <hip/hip_runtime.h>
#include <math.h>

#define BB 8
#define LL 196
#define DD 384
#define NDEPTH 24
#define NST 16
#define RRANK 24
#define HHID 1024
#define MROWS (BB*LL)   /* 1568 */
#define NCH 14
#define CHL 14

typedef float f32x4 __attribute__((ext_vector_type(4)));
typedef short s16x8 __attribute__((ext_vector_type(8)));
typedef short s16x4 __attribute__((ext_vector_type(4)));
typedef __bf16 b16x8 __attribute__((ext_vector_type(8)));
typedef unsigned short u16;
typedef unsigned int u32;

__device__ __forceinline__ float sigmoidf_(float x){ return 1.f/(1.f+__expf(-x)); }

__device__ __forceinline__ u16 f2bf(float f){
    u32 u = __builtin_bit_cast(u32, f);
    u32 r = (u + 0x7fffu + ((u >> 16) & 1u)) >> 16;   // RNE
    return (u16)r;
}
__device__ __forceinline__ float bf2f(u16 v){
    u32 u = ((u32)v) << 16;
    return __builtin_bit_cast(float, u);
}

// ---- MFMA wrapper: SFINAE hedge over builtin operand type ----
template<typename V>
__device__ __forceinline__ auto mfma_try(V a, V b, f32x4 c, int)
    -> decltype(__builtin_amdgcn_mfma_f32_16x16x32_bf16(a, b, c, 0, 0, 0))
{ return __builtin_amdgcn_mfma_f32_16x16x32_bf16(a, b, c, 0, 0, 0); }

template<typename V>
__device__ __forceinline__ f32x4 mfma_try(V a, V b, f32x4 c, long)
{
    return __builtin_amdgcn_mfma_f32_16x16x32_bf16(
        __builtin_bit_cast(b16x8, a), __builtin_bit_cast(b16x8, b), c, 0, 0, 0);
}
__device__ __forceinline__ f32x4 mfma_bf16(s16x8 a, s16x8 b, f32x4 c){ return mfma_try(a, b, c, 0); }

// ---------------- LayerNorm: BF=1 -> bf16 out, BF=0 -> f32 out ----------------
template<int BF>
__global__ __launch_bounds__(64) void ln_k(const float* __restrict__ X,
    const float* __restrict__ w, const float* __restrict__ b, void* __restrict__ Yv)
{
    int row = blockIdx.x;
    int lane = threadIdx.x;
    const float* x = X + (size_t)row*DD;
    float v[6]; float s=0.f, s2=0.f;
    #pragma unroll
    for (int j=0;j<6;j++){ float t = x[lane + j*64]; v[j]=t; s+=t; s2+=t*t; }
    #pragma unroll
    for (int o=32;o>=1;o>>=1){ s += __shfl_xor(s,o); s2 += __shfl_xor(s2,o); }
    float m = s*(1.f/DD);
    float var = s2*(1.f/DD) - m*m;
    float rstd = rsqrtf(var + 1e-5f);
    #pragma unroll
    for (int j=0;j<6;j++){
        int c = lane + j*64;
        float val = (v[j]-m)*rstd*w[c] + b[c];
        if (BF) ((u16*)Yv)[(size_t)row*DD + c] = f2bf(val);
        else    ((float*)Yv)[(size_t)row*DD + c] = val;
    }
}

// ---------------- Patch gather -> bf16 (B*L, 768) ----------------
__global__ void gather_k(const float* __restrict__ x, u16* __restrict__ P)
{
    int idx = blockIdx.x*blockDim.x + threadIdx.x;
    if (idx >= MROWS*768) return;
    int k = idx % 768;
    int bl = idx / 768;
    int l = bl % LL;
    int b = bl / LL;
    int c = k >> 8;
    int rem = k & 255;
    int dy = rem >> 4, dx = rem & 15;
    int py = l / 14, px = l % 14;
    P[idx] = f2bf(x[(((size_t)b*3 + c)*224 + (py*16+dy))*224 + (px*16+dx)]);
}

// ---------------- Causal depthwise conv (K=4) + SiLU: bf16 xz -> bf16 xab ----------------
__global__ void conv_silu_k(const u16* __restrict__ xzb,
    const float* __restrict__ cw, const float* __restrict__ cb,
    u16* __restrict__ xab)
{
    int idx = blockIdx.x*blockDim.x + threadIdx.x;
    if (idx >= MROWS*DD) return;
    int d = idx % DD;
    int bl = idx / DD;
    int l = bl % LL;
    int b = bl / LL;
    float acc = cb[d];
    #pragma unroll
    for (int k=0;k<4;k++){
        int ls = l + k - 3;
        if (ls >= 0) acc = fmaf(bf2f(xzb[(size_t)(b*LL+ls)*768 + d]), cw[d*4+k], acc);
    }
    float v = acc * sigmoidf_(acc);
    xab[idx] = f2bf(v);
}

// ---------------- MFMA bf16 GEMM, double-buffered, 1 barrier / K-step ----------------
// CFG 0: BM=64 waves 2x2 (frag 2x4) | CFG 1: BM=32 waves 1x4 (2x2) | CFG 2: BM=16 waves 1x4 (1x2)
// BN=128, BK=64.  B rows N-guarded (zero-filled) so any N<=BN*gx works.
// EPI: 0 plain f32 | 1 +bias f32 | 2 +resid f32 | 3 +resid+bias f32
//      4 dual silu(a1+b1)*(a2+b2)->bf16 | 6 plain bf16
__device__ __forceinline__ int swz(int row, int chunk){
    return (row << 7) + ((chunk ^ (row & 7)) << 4);
}

template<int EPI, bool WB, int CFG>
__global__ __launch_bounds__(256) void mgemm_k(
    const u16* __restrict__ A,
    const void* __restrict__ W1v, const void* __restrict__ W2v,
    const float* __restrict__ bias1, const float* __restrict__ bias2,
    float* __restrict__ Cf, u16* __restrict__ Cb,
    int M, int N, int K)
{
    constexpr int  BM   = (CFG==0)?64:(CFG==1)?32:16;
    constexpr int  FM   = (CFG==2)?1:2;
    constexpr int  FN   = (CFG==0)?4:2;
    constexpr int  NAR  = (BM+31)/32;
    constexpr bool DUAL = (EPI==4);
    constexpr int  ABY  = BM*128;
    constexpr int  BBY  = 128*128;
    __shared__ __attribute__((aligned(16))) char sm[2*ABY + 2*BBY + (DUAL ? 2*BBY : 0)];

    const int tid = threadIdx.x;
    const int row0 = blockIdx.y * BM;
    const int col0 = blockIdx.x << 7;
    const int w = tid >> 6, lane = tid & 63;
    const int wmo = (CFG==0) ? (w & 1)*32 : 0;
    const int wn  = (CFG==0) ? (w >> 1) : w;
    const int lr = lane & 15, lk = lane >> 4;
    const int ar0 = tid >> 3, ac8 = tid & 7;
    const bool apart = (CFG != 2) || (tid < 128);   // A-staging participation

    const u16*   W1b = (const u16*)W1v;
    const u16*   W2b = (const u16*)W2v;
    const float* W1f = (const float*)W1v;
    const float* W2f = (const float*)W2v;

    f32x4 acc[FM][FN] = {};
    f32x4 acc2[FM][FN] = {};

    s16x8 aval[NAR];
    s16x8 bval[4], b2val[4];
    float4 bvf[8], b2vf[8];

    auto loadT = [&](int kb){
        if (apart){
            #pragma unroll
            for (int i=0;i<NAR;i++){
                int gr = row0 + i*32 + ar0;
                if (gr < M) aval[i] = *(const s16x8*)(A + (size_t)gr*K + kb + ac8*8);
                else        aval[i] = s16x8{0,0,0,0,0,0,0,0};
            }
        }
        if (WB){
            #pragma unroll
            for (int i=0;i<4;i++){
                int gb = col0 + i*32 + ar0;
                if (gb < N) bval[i] = *(const s16x8*)(W1b + (size_t)gb*K + kb + ac8*8);
                else        bval[i] = s16x8{0,0,0,0,0,0,0,0};
            }
            if (DUAL){
                #pragma unroll
                for (int i=0;i<4;i++){
                    int gb = col0 + i*32 + ar0;
                    if (gb < N) b2val[i] = *(const s16x8*)(W2b + (size_t)gb*K + kb + ac8*8);
                    else        b2val[i] = s16x8{0,0,0,0,0,0,0,0};
                }
            }
        } else {
            #pragma unroll
            for (int i=0;i<8;i++){
                int s = i*256 + tid;
                int r = s >> 4, q = s & 15;
                int gb = col0 + r;
                if (gb < N) bvf[i] = *(const float4*)(W1f + (size_t)gb*K + kb + q*4);
                else        bvf[i] = float4{0,0,0,0};
            }
            if (DUAL){
                #pragma unroll
                for (int i=0;i<8;i++){
                    int s = i*256 + tid;
                    int r = s >> 4, q = s & 15;
                    int gb = col0 + r;
                    if (gb < N) b2vf[i] = *(const float4*)(W2f + (size_t)gb*K + kb + q*4);
                    else        b2vf[i] = float4{0,0,0,0};
                }
            }
        }
    };

    auto writeT = [&](char* bA, char* bB, char* bB2){
        if (apart){
            #pragma unroll
            for (int i=0;i<NAR;i++)
                *(s16x8*)(bA + swz(i*32 + ar0, ac8)) = aval[i];
        }
        if (WB){
            #pragma unroll
            for (int i=0;i<4;i++)
                *(s16x8*)(bB + swz(i*32 + ar0, ac8)) = bval[i];
            if (DUAL){
                #pragma unroll
                for (int i=0;i<4;i++)
                    *(s16x8*)(bB2 + swz(i*32 + ar0, ac8)) = b2val[i];
            }
        } else {
            #pragma unroll
            for (int i=0;i<8;i++){
                int s = i*256 + tid;
                int r = s >> 4, q = s & 15;
                float4 v = bvf[i];
                s16x4 cv = { (short)f2bf(v.x), (short)f2bf(v.y), (short)f2bf(v.z), (short)f2bf(v.w) };
                int off = (r << 7) + (((q >> 1) ^ (r & 7)) << 4) + ((q & 1) << 3);
                *(s16x4*)(bB + off) = cv;
            }
            if (DUAL){
                #pragma unroll
                for (int i=0;i<8;i++){
                    int s = i*256 + tid;
                    int r = s >> 4, q = s & 15;
                    float4 v = b2vf[i];
                    s16x4 cv = { (short)f2bf(v.x), (short)f2bf(v.y), (short)f2bf(v.z), (short)f2bf(v.w) };
                    int off = (r << 7) + (((q >> 1) ^ (r & 7)) << 4) + ((q & 1) << 3);
                    *(s16x4*)(bB2 + off) = cv;
                }
            }
        }
    };

    auto compute = [&](char* cA, char* cB, char* cB2){
        #pragma unroll
        for (int ks=0; ks<2; ks++){
            s16x8 af[FM], bfr[FN];
            #pragma unroll
            for (int m=0;m<FM;m++)
                af[m] = *(const s16x8*)(cA + swz(wmo + m*16 + lr, ks*4 + lk));
            #pragma unroll
            for (int n=0;n<FN;n++)
                bfr[n] = *(const s16x8*)(cB + swz(wn*(FN*16) + n*16 + lr, ks*4 + lk));
            #pragma unroll
            for (int m=0;m<FM;m++)
                #pragma unroll
                for (int n=0;n<FN;n++)
                    acc[m][n] = mfma_bf16(af[m], bfr[n], acc[m][n]);
            if (DUAL){
                s16x8 b2r[FN];
                #pragma unroll
                for (int n=0;n<FN;n++)
                    b2r[n] = *(const s16x8*)(cB2 + swz(wn*(FN*16) + n*16 + lr, ks*4 + lk));
                #pragma unroll
                for (int m=0;m<FM;m++)
                    #pragma unroll
                    for (int n=0;n<FN;n++)
                        acc2[m][n] = mfma_bf16(af[m], b2r[n], acc2[m][n]);
            }
        }
    };

    char* A0 = sm;          char* A1 = sm + ABY;
    char* B0 = sm + 2*ABY;  char* B1 = B0 + BBY;
    char* C0 = B1 + BBY;    char* C1 = C0 + BBY;   // dereferenced only when DUAL

    const int nkt = K >> 6;
    loadT(0);
    writeT(A0, B0, C0);
    __syncthreads();
    for (int kt=0; kt<nkt; kt++){
        const bool more = (kt+1 < nkt);
        if (more) loadT((kt+1) << 6);
        if (kt & 1){
            compute(A1, B1, C1);
            if (more) writeT(A0, B0, C0);
        } else {
            compute(A0, B0, C0);
            if (more) writeT(A1, B1, C1);
        }
        __syncthreads();
    }

    // ---- epilogue: row = row0 + wmo + m*16 + lk*4 + r ; col = col0 + wn*FN*16 + n*16 + lr
    #pragma unroll
    for (int n=0;n<FN;n++){
        int gc = col0 + wn*(FN*16) + n*16 + lr;
        if (gc >= N) continue;
        float b1 = 0.f, b2 = 0.f;
        if (EPI==1||EPI==3||EPI==4) b1 = bias1[gc];
        if (EPI==4) b2 = bias2[gc];
        #pragma unroll
        for (int m=0;m<FM;m++){
            #pragma unroll
            for (int r=0;r<4;r++){
                int gr = row0 + wmo + m*16 + lk*4 + r;
                if (gr >= M) continue;
                float v = acc[m][n][r];
                if (EPI==1||EPI==3) v += b1;
                if (EPI==2||EPI==3) v += Cf[(size_t)gr*N + gc];
                if (EPI==4){
                    float v1 = v + b1;
                    float v2 = acc2[m][n][r] + b2;
                    Cb[(size_t)gr*N + gc] = f2bf(v1 * sigmoidf_(v1) * v2);
                } else if (EPI==6){
                    Cb[(size_t)gr*N + gc] = f2bf(v);
                } else {
                    Cf[(size_t)gr*N + gc] = v;
                }
            }
        }
    }
}

// ---------------- fp32 -> bf16 weight conversion ----------------
__global__ void cvtw_k(const float* __restrict__ s, u16* __restrict__ d, int n)
{
    int i = blockIdx.x*blockDim.x + threadIdx.x;
    int idx = i*4;
    if (idx + 4 <= n){
        float4 v = *(const float4*)(s + idx);
        s16x4 cv = { (short)f2bf(v.x), (short)f2bf(v.y), (short)f2bf(v.z), (short)f2bf(v.w) };
        *(s16x4*)(d + idx) = cv;
    } else {
        for (int j=idx;j<n;j++) d[j] = f2bf(s[j]);
    }
}

// ---------------- Scan phase A (dt_proj fused): per-chunk P (decay) and S (local state) ----------------
__global__ __launch_bounds__(384) void scanA_k(
    const float* __restrict__ dbc, const u16* __restrict__ xab,
    const float* __restrict__ dtw, const float* __restrict__ dtb,
    const float* __restrict__ a_log,
    float* __restrict__ Pout, float* __restrict__ Sout)
{
    int b = blockIdx.x / NCH;
    int c = blockIdx.x % NCH;
    int d = threadIdx.x;
    __shared__ float Ds[CHL][56];
    for (int t = threadIdx.x; t < CHL*56; t += 384){
        int j = t/56, q = t%56;
        Ds[j][q] = dbc[(size_t)(b*LL + c*CHL + j)*56 + q];
    }
    __syncthreads();
    float dtwr[RRANK];
    #pragma unroll
    for (int r=0;r<RRANK;r++) dtwr[r] = dtw[d*RRANK + r];
    float dtbv = dtb[d];
    float Aa[NST];
    #pragma unroll
    for (int n=0;n<NST;n++) Aa[n] = -__expf(a_log[d*NST+n]);
    float hst[NST], P[NST];
    #pragma unroll
    for (int n=0;n<NST;n++){ hst[n]=0.f; P[n]=1.f; }
    for (int j=0;j<CHL;j++){
        int row = b*LL + c*CHL + j;
        float t = dtbv;
        #pragma unroll
        for (int r=0;r<RRANK;r++) t = fmaf(dtwr[r], Ds[j][r], t);
        float dtv = (t > 20.f) ? t : log1pf(__expf(t));
        float xv  = bf2f(xab[(size_t)row*DD + d]);
        float du = dtv*xv;
        #pragma unroll
        for (int n=0;n<NST;n++){
            float e = __expf(dtv*Aa[n]);
            hst[n] = fmaf(hst[n], e, du*Ds[j][24+n]);
            P[n] *= e;
        }
    }
    size_t base = ((size_t)(b*NCH + c)*DD + d)*NST;
    #pragma unroll
    for (int n=0;n<NST;n++){ Pout[base+n]=P[n]; Sout[base+n]=hst[n]; }
}

// ---------------- Scan phase C: chunk-prefix combine + replay + D_skip + SiLU(z) -> bf16 yg ----------------
__global__ __launch_bounds__(384) void scanC_k(
    const float* __restrict__ dbc, const u16* __restrict__ xab,
    const float* __restrict__ dtw, const float* __restrict__ dtb,
    const float* __restrict__ a_log,
    const float* __restrict__ Pin, const float* __restrict__ Sin,
    const u16* __restrict__ xzb, const float* __restrict__ dskip,
    u16* __restrict__ yg)
{
    int b = blockIdx.x / NCH;
    int c = blockIdx.x % NCH;
    int d = threadIdx.x;
    __shared__ float Ds[CHL][56];
    for (int t = threadIdx.x; t < CHL*56; t += 384){
        int j = t/56, q = t%56;
        Ds[j][q] = dbc[(size_t)(b*LL + c*CHL + j)*56 + q];
    }
    __syncthreads();
    // ---- chunk-prefix: h0 for chunk c = combine of chunks 0..c-1 (replaces scanB)
    float hst[NST];
    #pragma unroll
    for (int n=0;n<NST;n++) hst[n]=0.f;
    for (int cc=0; cc<c; cc++){
        size_t base = ((size_t)(b*NCH + cc)*DD + d)*NST;
        #pragma unroll
        for (int n=0;n<NST;n++)
            hst[n] = fmaf(Pin[base+n], hst[n], Sin[base+n]);
    }
    float dtwr[RRANK];
    #pragma unroll
    for (int r=0;r<RRANK;r++) dtwr[r] = dtw[d*RRANK + r];
    float dtbv = dtb[d];
    float Aa[NST];
    #pragma unroll
    for (int n=0;n<NST;n++) Aa[n] = -__expf(a_log[d*NST+n]);
    float dsk = dskip[d];
    for (int j=0;j<CHL;j++){
        int row = b*LL + c*CHL + j;
        float t = dtbv;
        #pragma unroll
        for (int r=0;r<RRANK;r++) t = fmaf(dtwr[r], Ds[j][r], t);
        float dtv = (t > 20.f) ? t : log1pf(__expf(t));
        float xv  = bf2f(xab[(size_t)row*DD + d]);
        float du = dtv*xv;
        float y = 0.f;
        #pragma unroll
        for (int n=0;n<NST;n++){
            float e = __expf(dtv*Aa[n]);
            hst[n] = fmaf(hst[n], e, du*Ds[j][24+n]);
            y = fmaf(hst[n], Ds[j][40+n], y);
        }
        float zv = bf2f(xzb[(size_t)row*768 + 384 + d]);
        float g = zv * sigmoidf_(zv);
        yg[(size_t)row*DD + d] = f2bf((y + dsk*xv)*g);
    }
}

// ---------------- host-side MFMA launcher (WB gating) ----------------
template<int EPI, int CFG>
static void mg(bool wb, dim3 g, hipStream_t s, const void* A,
               const void* Wb, const void* Wf, const void* W2b, const void* W2f,
               const float* b1, const float* b2, float* Cf, u16* Cb,
               int M, int N, int K)
{
    if (wb) mgemm_k<EPI,true ,CFG><<<g,256,0,s>>>((const u16*)A, Wb, W2b, b1, b2, Cf, Cb, M, N, K);
    else    mgemm_k<EPI,false,CFG><<<g,256,0,s>>>((const u16*)A, Wf, W2f, b1, b2, Cf, Cb, M, N, K);
}

extern "C" void kernel_launch(void* const* d_in, const int* in_sizes, int n_in,
                              void* d_out, int out_size, void* d_ws, size_t ws_size,
                              hipStream_t stream)
{
    const float* x         = (const float*)d_in[0];
    const float* patch_w   = (const float*)d_in[1];
    const float* patch_b   = (const float*)d_in[2];
    const float* norm1_w   = (const float*)d_in[3];
    const float* norm1_b   = (const float*)d_in[4];
    const float* in_proj_w = (const float*)d_in[5];
    const float* conv_w    = (const float*)d_in[6];
    const float* conv_b    = (const float*)d_in[7];
    const float* x_proj_w  = (const float*)d_in[8];
    const float* dt_w      = (const float*)d_in[9];
    const float* dt_b      = (const float*)d_in[10];
    const float* A_log     = (const float*)d_in[11];
    const float* D_skip    = (const float*)d_in[12];
    const float* out_w     = (const float*)d_in[13];
    const float* norm2_w   = (const float*)d_in[14];
    const float* norm2_b   = (const float*)d_in[15];
    const float* w1_w      = (const float*)d_in[16];
    const float* w1_b      = (const float*)d_in[17];
    const float* w2_w      = (const float*)d_in[18];
    const float* w2_b      = (const float*)d_in[19];
    const float* w3_w      = (const float*)d_in[20];
    const float* w3_b      = (const float*)d_in[21];
    const float* normf_w   = (const float*)d_in[22];
    const float* normf_b   = (const float*)d_in[23];

    char* wsb = (char*)d_ws;
    size_t o = 0;
    auto take = [&](size_t bytes) -> char* {
        char* p = wsb + o;
        o += (bytes + 255) & ~(size_t)255;
        return p;
    };

    float* h    = (float*)take((size_t)602112*4);
    float* dbc  = (float*)take((size_t)87808*4);
    float* Pb   = (float*)take((size_t)688128*4);
    float* Sb   = (float*)take((size_t)688128*4);
    u16*  xzb   = (u16*)take((size_t)1204224*2);
    u16*  xn    = (u16*)take((size_t)602112*2);
    u16*  xab   = (u16*)take((size_t)602112*2);
    u16*  yg    = (u16*)take((size_t)602112*2);
    u16*  hid   = (u16*)take((size_t)1605632*2);
    u16*  patches = hid;   // alias: consumed before hid is produced

    const size_t NPW = 294912, NIN = 7077888, NOUT = 3538944,
                 NW1 = 9437184, NW2 = 9437184, NW3 = 9437184, NXP = 516096;
    u16* wcP = (u16*)take(NPW*2);
    u16* wcI = (u16*)take(NIN*2);
    u16* wcO = (u16*)take(NOUT*2);
    u16* wc1 = (u16*)take(NW1*2);
    u16* wc2 = (u16*)take(NW2*2);
    u16* wc3 = (u16*)take(NW3*2);
    u16* wcX = (u16*)take(NXP*2);
    bool wb = (ws_size >= o);

    if (wb){
        cvtw_k<<<(int)((NPW/4+255)/256), 256, 0, stream>>>(patch_w, wcP, (int)NPW);
        cvtw_k<<<(int)((NIN/4+255)/256), 256, 0, stream>>>(in_proj_w, wcI, (int)NIN);
        cvtw_k<<<(int)((NOUT/4+255)/256),256, 0, stream>>>(out_w, wcO, (int)NOUT);
        cvtw_k<<<(int)((NW1/4+255)/256), 256, 0, stream>>>(w1_w, wc1, (int)NW1);
        cvtw_k<<<(int)((NW2/4+255)/256), 256, 0, stream>>>(w2_w, wc2, (int)NW2);
        cvtw_k<<<(int)((NW3/4+255)/256), 256, 0, stream>>>(w3_w, wc3, (int)NW3);
        cvtw_k<<<(int)((NXP/4+255)/256), 256, 0, stream>>>(x_proj_w, wcX, (int)NXP);
    }

    const int GY32 = (MROWS + 31)/32;   // 49
    const int GY16 = (MROWS + 15)/16;   // 98

    // Patch embedding
    gather_k<<<(MROWS*768+255)/256, 256, 0, stream>>>(x, patches);
    mg<1,2>(wb, dim3(3,GY16), stream, patches, wcP, patch_w, nullptr, nullptr,
            patch_b, nullptr, h, nullptr, MROWS, DD, 768);

    for (int i=0;i<NDEPTH;i++){
        ln_k<1><<<MROWS, 64, 0, stream>>>(h, norm1_w + i*DD, norm1_b + i*DD, xn);
        mg<6,1>(wb, dim3(6,GY32), stream, xn, wcI + (size_t)i*768*DD, in_proj_w + (size_t)i*768*DD,
                nullptr, nullptr, nullptr, nullptr, nullptr, xzb, MROWS, 768, DD);
        conv_silu_k<<<(MROWS*DD+255)/256, 256, 0, stream>>>(xzb, conv_w + i*DD*4, conv_b + i*DD, xab);
        mg<0,2>(wb, dim3(1,GY16), stream, xab, wcX + (size_t)i*56*DD, x_proj_w + (size_t)i*56*DD,
                nullptr, nullptr, nullptr, nullptr, dbc, nullptr, MROWS, 56, DD);
        scanA_k<<<BB*NCH, 384, 0, stream>>>(dbc, xab, dt_w + (size_t)i*DD*RRANK, dt_b + i*DD,
                                            A_log + (size_t)i*DD*NST, Pb, Sb);
        scanC_k<<<BB*NCH, 384, 0, stream>>>(dbc, xab, dt_w + (size_t)i*DD*RRANK, dt_b + i*DD,
                                            A_log + (size_t)i*DD*NST, Pb, Sb, xzb, D_skip + i*DD, yg);
        mg<2,2>(wb, dim3(3,GY16), stream, yg, wcO + (size_t)i*DD*DD, out_w + (size_t)i*DD*DD,
                nullptr, nullptr, nullptr, nullptr, h, nullptr, MROWS, DD, DD);
        ln_k<1><<<MROWS, 64, 0, stream>>>(h, norm2_w + i*DD, norm2_b + i*DD, xn);
        mg<4,1>(wb, dim3(8,GY32), stream, xn,
                wc1 + (size_t)i*HHID*DD, w1_w + (size_t)i*HHID*DD,
                wc2 + (size_t)i*HHID*DD, w2_w + (size_t)i*HHID*DD,
                w1_b + i*HHID, w2_b + i*HHID, nullptr, hid, MROWS, HHID, DD);
        mg<3,2>(wb, dim3(3,GY16), stream, hid, wc3 + (size_t)i*DD*HHID, w3_w + (size_t)i*DD*HHID,
                nullptr, nullptr, w3_b + i*DD, nullptr, h, nullptr, MROWS, DD, HHID);
    }

    ln_k<0><<<MROWS, 64, 0, stream>>>(h, normf_w, normf_b, d_out);
}